// Round 1
// baseline (123.903 us; speedup 1.0000x reference)
//
#include <hip/hip_runtime.h>

#define NN 4096
#define LOG2E 1.44269504088896340736f
#define KC 8            // k-chunks for B partials
#define KCH (NN / KC)   // 512
#define IC 8            // i-chunks for column softmax partials
#define ICH (NN / IC)   // 512

// ---------------------------------------------------------------------------
// Kernel 1: partial row sums  Bpart[kc][b][i] = sum_{k in chunk} |s_i - s_k|
// (|s_i - s_k| == |scores_i - scores_k|, sign drops under abs)
// grid: (NN/256, KC, nb), block 256
__global__ __launch_bounds__(256) void k_bpart(const float* __restrict__ scores,
                                               float* __restrict__ bpart, int nb) {
    __shared__ float sch[KCH];
    const int b = blockIdx.z, kc = blockIdx.y, t = threadIdx.x;
    const float* srow = scores + (size_t)b * NN;
    for (int q = t; q < KCH; q += 256) sch[q] = srow[kc * KCH + q];
    __syncthreads();
    const int i = blockIdx.x * 256 + t;
    const float si = srow[i];
    float a0 = 0.f, a1 = 0.f, a2 = 0.f, a3 = 0.f;
    for (int k = 0; k < KCH; k += 4) {
        float4 v = *reinterpret_cast<const float4*>(&sch[k]);
        a0 += fabsf(si - v.x);
        a1 += fabsf(si - v.y);
        a2 += fabsf(si - v.z);
        a3 += fabsf(si - v.w);
    }
    bpart[((size_t)kc * nb + b) * NN + i] = (a0 + a1) + (a2 + a3);
}

// ---------------------------------------------------------------------------
// Kernel 2: reduce B partials; emit log2-domain row constants
//   u[b,i] = -scores * log2e   (so logit2[i,j] = u_i * c_j - v_i)
//   v[b,i] =  B_i * log2e
__global__ __launch_bounds__(256) void k_rowstats(const float* __restrict__ scores,
                                                  const float* __restrict__ bpart,
                                                  float* __restrict__ u,
                                                  float* __restrict__ vl, int nb) {
    const size_t idx = (size_t)blockIdx.x * 256 + threadIdx.x;
    const size_t str = (size_t)nb * NN;
    float s = 0.f;
#pragma unroll
    for (int c = 0; c < KC; c++) s += bpart[c * str + idx];
    u[idx] = -scores[idx] * LOG2E;
    vl[idx] = s * LOG2E;
}

// ---------------------------------------------------------------------------
// Kernel 3: per-column partial max and partial sum-of-exp2 over an i-chunk.
// grid: (NN/256 cols, IC, nb), block 256; one thread per column j.
__global__ __launch_bounds__(256) void k_colpart(const float* __restrict__ u,
                                                 const float* __restrict__ vl,
                                                 float* __restrict__ mpart,
                                                 float* __restrict__ zpart, int nb) {
    __shared__ float su[ICH], sv[ICH];
    const int b = blockIdx.z, jc = blockIdx.x, ic = blockIdx.y, t = threadIdx.x;
    const size_t base = (size_t)b * NN + (size_t)ic * ICH;
    for (int q = t; q < ICH; q += 256) { su[q] = u[base + q]; sv[q] = vl[base + q]; }
    __syncthreads();
    const int j = jc * 256 + t;
    const float cj = (float)(NN - 1 - 2 * j);
    float m0 = -3.4e38f, m1 = -3.4e38f, m2 = -3.4e38f, m3 = -3.4e38f;
    for (int k = 0; k < ICH; k += 4) {
        float4 uu = *reinterpret_cast<const float4*>(&su[k]);
        float4 vv = *reinterpret_cast<const float4*>(&sv[k]);
        m0 = fmaxf(m0, fmaf(uu.x, cj, -vv.x));
        m1 = fmaxf(m1, fmaf(uu.y, cj, -vv.y));
        m2 = fmaxf(m2, fmaf(uu.z, cj, -vv.z));
        m3 = fmaxf(m3, fmaf(uu.w, cj, -vv.w));
    }
    const float m = fmaxf(fmaxf(m0, m1), fmaxf(m2, m3));
    float z0 = 0.f, z1 = 0.f, z2 = 0.f, z3 = 0.f;
    for (int k = 0; k < ICH; k += 4) {
        float4 uu = *reinterpret_cast<const float4*>(&su[k]);
        float4 vv = *reinterpret_cast<const float4*>(&sv[k]);
        z0 += exp2f(fmaf(uu.x, cj, -vv.x) - m);
        z1 += exp2f(fmaf(uu.y, cj, -vv.y) - m);
        z2 += exp2f(fmaf(uu.z, cj, -vv.z) - m);
        z3 += exp2f(fmaf(uu.w, cj, -vv.w) - m);
    }
    const size_t o = ((size_t)ic * nb + b) * NN + j;
    mpart[o] = m;
    zpart[o] = (z0 + z1) + (z2 + z3);
}

// ---------------------------------------------------------------------------
// Kernel 4: merge IC (m, Z) partials -> column max mL[j] and 1/Z[j]
__global__ __launch_bounds__(256) void k_colfinal(const float* __restrict__ mpart,
                                                  const float* __restrict__ zpart,
                                                  float* __restrict__ ml,
                                                  float* __restrict__ rz, int nb) {
    const size_t idx = (size_t)blockIdx.x * 256 + threadIdx.x;
    const size_t str = (size_t)nb * NN;
    float mv[IC];
    float m = -3.4e38f;
#pragma unroll
    for (int c = 0; c < IC; c++) { mv[c] = mpart[c * str + idx]; m = fmaxf(m, mv[c]); }
    float z = 0.f;
#pragma unroll
    for (int c = 0; c < IC; c++) z += zpart[c * str + idx] * exp2f(mv[c] - m);
    ml[idx] = m;
    rz[idx] = 1.0f / z;
}

// ---------------------------------------------------------------------------
// Kernel 5: write out[b,i,j] = exp2(u_i*c_j - v_i - m_j) * rZ_j
// grid: (NN/1024 col-groups, NN/32 row-groups, nb), block 256.
// Each thread owns 4 consecutive columns (float4 store), loops 32 rows.
__global__ __launch_bounds__(256) void k_out(const float* __restrict__ u,
                                             const float* __restrict__ vl,
                                             const float* __restrict__ ml,
                                             const float* __restrict__ rz,
                                             float* __restrict__ out, int nb) {
    __shared__ float su[32], sv[32];
    const int b = blockIdx.z, jc = blockIdx.x, t = threadIdx.x;
    const int i0 = blockIdx.y * 32;
    if (t < 32) {
        su[t] = u[(size_t)b * NN + i0 + t];
        sv[t] = vl[(size_t)b * NN + i0 + t];
    }
    const int j = jc * 1024 + t * 4;
    const float4 m4 = *reinterpret_cast<const float4*>(ml + (size_t)b * NN + j);
    const float4 z4 = *reinterpret_cast<const float4*>(rz + (size_t)b * NN + j);
    const float c0 = (float)(NN - 1 - 2 * j);
    const float c1 = c0 - 2.f, c2 = c0 - 4.f, c3 = c0 - 6.f;
    __syncthreads();
    float* orow = out + ((size_t)b * NN + i0) * NN + j;
#pragma unroll 4
    for (int r = 0; r < 32; r++) {
        const float ui = su[r], vi = sv[r];
        float4 o;
        o.x = exp2f(fmaf(ui, c0, -vi) - m4.x) * z4.x;
        o.y = exp2f(fmaf(ui, c1, -vi) - m4.y) * z4.y;
        o.z = exp2f(fmaf(ui, c2, -vi) - m4.z) * z4.z;
        o.w = exp2f(fmaf(ui, c3, -vi) - m4.w) * z4.w;
        *reinterpret_cast<float4*>(orow + (size_t)r * NN) = o;
    }
}

// ---------------------------------------------------------------------------
extern "C" void kernel_launch(void* const* d_in, const int* in_sizes, int n_in,
                              void* d_out, int out_size, void* d_ws, size_t ws_size,
                              hipStream_t stream) {
    const float* scores = (const float*)d_in[0];
    float* out = (float*)d_out;
    const int nb = in_sizes[0] / NN;          // 4 batches
    const size_t S = (size_t)nb * NN;

    float* ws    = (float*)d_ws;              // total 28*S floats = 1.75 MiB
    float* bpart = ws;                        // KC*S
    float* u     = bpart + (size_t)KC * S;    // S
    float* vl    = u + S;                     // S
    float* mpart = vl + S;                    // IC*S
    float* zpart = mpart + (size_t)IC * S;    // IC*S
    float* ml    = zpart + (size_t)IC * S;    // S
    float* rz    = ml + S;                    // S

    hipLaunchKernelGGL(k_bpart, dim3(NN / 256, KC, nb), dim3(256), 0, stream,
                       scores, bpart, nb);
    hipLaunchKernelGGL(k_rowstats, dim3((unsigned)(S / 256)), dim3(256), 0, stream,
                       scores, bpart, u, vl, nb);
    hipLaunchKernelGGL(k_colpart, dim3(NN / 256, IC, nb), dim3(256), 0, stream,
                       u, vl, mpart, zpart, nb);
    hipLaunchKernelGGL(k_colfinal, dim3((unsigned)(S / 256)), dim3(256), 0, stream,
                       mpart, zpart, ml, rz, nb);
    hipLaunchKernelGGL(k_out, dim3(NN / 1024, NN / 32, nb), dim3(256), 0, stream,
                       u, vl, ml, rz, out, nb);
}

// Round 3
// 67.695 us; speedup vs baseline: 1.8303x; 1.8303x over previous
//
#include <hip/hip_runtime.h>

#define NN 4096
#define LOG2E 1.44269504088896340736f
#define KC 8            // k-chunks for B partials
#define KCH (NN / KC)   // 512
#define IC 16           // i-chunks for column softmax partials
#define ICH (NN / IC)   // 256

#define EXP2(x) __builtin_amdgcn_exp2f(x)

// ---------------------------------------------------------------------------
// Kernel 1: partial row sums  Bpart[kc][b][i] = sum_{k in chunk} |s_i - s_k|
// (|s_i - s_k| == |scores_i - scores_k|, sign drops under abs)
// grid: (NN/512, KC, nb), block 256; each thread owns rows i0 and i0+256.
__global__ __launch_bounds__(256) void k_bpart(const float* __restrict__ scores,
                                               float* __restrict__ bpart, int nb) {
    __shared__ float sch[KCH];
    const int b = blockIdx.z, kc = blockIdx.y, t = threadIdx.x;
    const float* srow = scores + (size_t)b * NN;
    for (int q = t; q < KCH; q += 256) sch[q] = srow[kc * KCH + q];
    __syncthreads();
    const int i0 = blockIdx.x * 512 + t;
    const float s0 = srow[i0], s1 = srow[i0 + 256];
    float a00 = 0.f, a01 = 0.f, a02 = 0.f, a03 = 0.f;
    float a10 = 0.f, a11 = 0.f, a12 = 0.f, a13 = 0.f;
    for (int k = 0; k < KCH; k += 4) {
        float4 v = *reinterpret_cast<const float4*>(&sch[k]);
        a00 += fabsf(s0 - v.x); a01 += fabsf(s0 - v.y);
        a02 += fabsf(s0 - v.z); a03 += fabsf(s0 - v.w);
        a10 += fabsf(s1 - v.x); a11 += fabsf(s1 - v.y);
        a12 += fabsf(s1 - v.z); a13 += fabsf(s1 - v.w);
    }
    const size_t o = ((size_t)kc * nb + b) * NN + i0;
    bpart[o]       = (a00 + a01) + (a02 + a03);
    bpart[o + 256] = (a10 + a11) + (a12 + a13);
}

// ---------------------------------------------------------------------------
// Kernel 2: reduce B partials; emit log2-domain row constants
//   u[b,i] = -scores * log2e   (so logit2[i,j] = u_i * c_j - v_i)
//   v[b,i] =  B_i * log2e
__global__ __launch_bounds__(256) void k_rowstats(const float* __restrict__ scores,
                                                  const float* __restrict__ bpart,
                                                  float* __restrict__ u,
                                                  float* __restrict__ vl, int nb) {
    const size_t idx = (size_t)blockIdx.x * 256 + threadIdx.x;
    const size_t str = (size_t)nb * NN;
    float s = 0.f;
#pragma unroll
    for (int c = 0; c < KC; c++) s += bpart[c * str + idx];
    u[idx] = -scores[idx] * LOG2E;
    vl[idx] = s * LOG2E;
}

// ---------------------------------------------------------------------------
// Kernel 3: per-column partial max and partial sum-of-exp2 over an i-chunk.
// grid: (NN/512 col-groups, IC, nb), block 256; thread owns cols j0, j0+256.
__global__ __launch_bounds__(256) void k_colpart(const float* __restrict__ u,
                                                 const float* __restrict__ vl,
                                                 float* __restrict__ mpart,
                                                 float* __restrict__ zpart, int nb) {
    __shared__ float su[ICH], sv[ICH];
    const int b = blockIdx.z, jc = blockIdx.x, ic = blockIdx.y, t = threadIdx.x;
    const size_t base = (size_t)b * NN + (size_t)ic * ICH;
    su[t] = u[base + t];
    sv[t] = -vl[base + t];          // store negated: x = fma(u, c, sv)
    __syncthreads();
    const int j0 = jc * 512 + t;
    const float c0 = (float)(NN - 1 - 2 * j0);
    const float c1 = c0 - 512.f;    // column j0 + 256
    float m00 = -3.4e38f, m01 = -3.4e38f, m10 = -3.4e38f, m11 = -3.4e38f;
    for (int k = 0; k < ICH; k += 2) {
        float ua = su[k], va = sv[k], ub = su[k + 1], vb = sv[k + 1];
        m00 = fmaxf(m00, fmaf(ua, c0, va));
        m01 = fmaxf(m01, fmaf(ub, c0, vb));
        m10 = fmaxf(m10, fmaf(ua, c1, va));
        m11 = fmaxf(m11, fmaf(ub, c1, vb));
    }
    const float m0 = fmaxf(m00, m01), m1 = fmaxf(m10, m11);
    float z00 = 0.f, z01 = 0.f, z10 = 0.f, z11 = 0.f;
    for (int k = 0; k < ICH; k += 2) {
        float ua = su[k], va = sv[k], ub = su[k + 1], vb = sv[k + 1];
        z00 += EXP2(fmaf(ua, c0, va) - m0);
        z01 += EXP2(fmaf(ub, c0, vb) - m0);
        z10 += EXP2(fmaf(ua, c1, va) - m1);
        z11 += EXP2(fmaf(ub, c1, vb) - m1);
    }
    const size_t o = ((size_t)ic * nb + b) * NN + j0;
    mpart[o] = m0;         mpart[o + 256] = m1;
    zpart[o] = z00 + z01;  zpart[o + 256] = z10 + z11;
}

// ---------------------------------------------------------------------------
// Kernel 4: merge IC (m, Z) partials -> column max ml[j] and 1/Z[j]
__global__ __launch_bounds__(256) void k_colfinal(const float* __restrict__ mpart,
                                                  const float* __restrict__ zpart,
                                                  float* __restrict__ ml,
                                                  float* __restrict__ rz, int nb) {
    const size_t idx = (size_t)blockIdx.x * 256 + threadIdx.x;
    const size_t str = (size_t)nb * NN;
    float mv[IC];
    float m = -3.4e38f;
#pragma unroll
    for (int c = 0; c < IC; c++) { mv[c] = mpart[c * str + idx]; m = fmaxf(m, mv[c]); }
    float z = 0.f;
#pragma unroll
    for (int c = 0; c < IC; c++) z += zpart[c * str + idx] * EXP2(mv[c] - m);
    ml[idx] = m;
    rz[idx] = 1.0f / z;
}

// ---------------------------------------------------------------------------
// Kernel 5: write out[b,i,j] = exp2(u_i*c_j - v_i - m_j) * rZ_j
// grid: (NN/1024 col-groups, NN/32 row-groups, nb), block 256.
// Each thread owns 4 consecutive columns (float4 store), loops 32 rows.
__global__ __launch_bounds__(256) void k_out(const float* __restrict__ u,
                                             const float* __restrict__ vl,
                                             const float* __restrict__ ml,
                                             const float* __restrict__ rz,
                                             float* __restrict__ out, int nb) {
    __shared__ float su[32], sv[32];
    const int b = blockIdx.z, jc = blockIdx.x, t = threadIdx.x;
    const int i0 = blockIdx.y * 32;
    if (t < 32) {
        su[t] = u[(size_t)b * NN + i0 + t];
        sv[t] = vl[(size_t)b * NN + i0 + t];
    }
    const int j = jc * 1024 + t * 4;
    const float4 m4 = *reinterpret_cast<const float4*>(ml + (size_t)b * NN + j);
    const float4 z4 = *reinterpret_cast<const float4*>(rz + (size_t)b * NN + j);
    const float c0 = (float)(NN - 1 - 2 * j);
    const float c1 = c0 - 2.f, c2 = c0 - 4.f, c3 = c0 - 6.f;
    __syncthreads();
    float* orow = out + ((size_t)b * NN + i0) * NN + j;
#pragma unroll 4
    for (int r = 0; r < 32; r++) {
        const float ui = su[r], nvi = -sv[r];
        // fold -v_i - m_j into one addend per column
        const float d0 = nvi - m4.x, d1 = nvi - m4.y;
        const float d2 = nvi - m4.z, d3 = nvi - m4.w;
        float4 o;
        o.x = EXP2(fmaf(ui, c0, d0)) * z4.x;
        o.y = EXP2(fmaf(ui, c1, d1)) * z4.y;
        o.z = EXP2(fmaf(ui, c2, d2)) * z4.z;
        o.w = EXP2(fmaf(ui, c3, d3)) * z4.w;
        *reinterpret_cast<float4*>(orow + (size_t)r * NN) = o;
    }
}

// ---------------------------------------------------------------------------
extern "C" void kernel_launch(void* const* d_in, const int* in_sizes, int n_in,
                              void* d_out, int out_size, void* d_ws, size_t ws_size,
                              hipStream_t stream) {
    const float* scores = (const float*)d_in[0];
    float* out = (float*)d_out;
    const int nb = in_sizes[0] / NN;          // 4 batches
    const size_t S = (size_t)nb * NN;

    // ws layout (floats): u(S) vl(S) ml(S) rz(S) | P region (reused):
    //   bpart needs KC*S; later mpart(IC*S)+zpart(IC*S) alias the same region.
    float* ws    = (float*)d_ws;
    float* u     = ws;
    float* vl    = u + S;
    float* ml    = vl + S;
    float* rz    = ml + S;
    float* P     = rz + S;                    // max(KC, 2*IC)*S floats
    float* bpart = P;                         // KC*S (dead after k_rowstats)
    float* mpart = P;                         // IC*S
    float* zpart = P + (size_t)IC * S;        // IC*S

    hipLaunchKernelGGL(k_bpart, dim3(NN / 512, KC, nb), dim3(256), 0, stream,
                       scores, bpart, nb);
    hipLaunchKernelGGL(k_rowstats, dim3((unsigned)(S / 256)), dim3(256), 0, stream,
                       scores, bpart, u, vl, nb);
    hipLaunchKernelGGL(k_colpart, dim3(NN / 512, IC, nb), dim3(256), 0, stream,
                       u, vl, mpart, zpart, nb);
    hipLaunchKernelGGL(k_colfinal, dim3((unsigned)(S / 256)), dim3(256), 0, stream,
                       mpart, zpart, ml, rz, nb);
    hipLaunchKernelGGL(k_out, dim3(NN / 1024, NN / 32, nb), dim3(256), 0, stream,
                       u, vl, ml, rz, out, nb);
}

// Round 4
// 67.694 us; speedup vs baseline: 1.8303x; 1.0000x over previous
//
#include <hip/hip_runtime.h>

#define NN 4096
#define LOG2E 1.44269504088896340736f
#define EXP2(x) __builtin_amdgcn_exp2f(x)

// ---------------------------------------------------------------------------
// Kernel A: per-row stats (fused old k_bpart + k_rowstats).
// Grid (NN/64, nb), block 256. Block stages the full 4096-score row (16 KB),
// 4 threads per row each sum a k-quarter of |s_i - s_k|, LDS-merge, emit
//   u[b,i] = -scores_i * log2e,  vl[b,i] = B_i * log2e.
__global__ __launch_bounds__(256) void k_rows(const float* __restrict__ scores,
                                              float* __restrict__ u,
                                              float* __restrict__ vl, int nb) {
    __shared__ float sch[NN];
    __shared__ float part[4][64];
    const int b = blockIdx.y, t = threadIdx.x;
    const float* srow = scores + (size_t)b * NN;
    for (int q = t * 4; q < NN; q += 1024)
        *reinterpret_cast<float4*>(&sch[q]) =
            *reinterpret_cast<const float4*>(&srow[q]);
    __syncthreads();
    const int r = t & 63;                  // row within block
    const int q = t >> 6;                  // k-quarter (uniform per wave)
    const float si = sch[blockIdx.x * 64 + r];
    float a0=0.f,a1=0.f,a2=0.f,a3=0.f,a4=0.f,a5=0.f,a6=0.f,a7=0.f;
    const int k0 = q * (NN / 4);
    for (int k = k0; k < k0 + NN / 4; k += 8) {
        float4 x = *reinterpret_cast<const float4*>(&sch[k]);
        float4 y = *reinterpret_cast<const float4*>(&sch[k + 4]);
        a0 += fabsf(si - x.x); a1 += fabsf(si - x.y);
        a2 += fabsf(si - x.z); a3 += fabsf(si - x.w);
        a4 += fabsf(si - y.x); a5 += fabsf(si - y.y);
        a6 += fabsf(si - y.z); a7 += fabsf(si - y.w);
    }
    part[q][r] = ((a0 + a1) + (a2 + a3)) + ((a4 + a5) + (a6 + a7));
    __syncthreads();
    if (t < 64) {
        const int ii = blockIdx.x * 64 + t;
        const float B = (part[0][t] + part[1][t]) + (part[2][t] + part[3][t]);
        u[(size_t)b * NN + ii]  = -sch[ii] * LOG2E;
        vl[(size_t)b * NN + ii] = B * LOG2E;
    }
}

// ---------------------------------------------------------------------------
// Kernel B: per-column softmax constant (fused old k_colpart + k_colfinal).
// Grid (NN/32, nb), block 256. Stage u and -v in LDS (32 KB); 8 threads per
// column, each scans 512 i's; two passes (max, sum-of-exp2) with LDS merges.
// Emits w[b,j] = -m_j - log2(Z_j) so out = exp2(u_i*c_j - v_i + w_j).
__global__ __launch_bounds__(256) void k_cols(const float* __restrict__ u,
                                              const float* __restrict__ vl,
                                              float* __restrict__ w, int nb) {
    __shared__ float su[NN];
    __shared__ float sv[NN];
    __shared__ float pm[8][32];
    __shared__ float pz[8][32];
    __shared__ float fm[32];
    const int b = blockIdx.y, t = threadIdx.x;
    const size_t base = (size_t)b * NN;
    for (int q4 = t * 4; q4 < NN; q4 += 1024) {
        float4 uu = *reinterpret_cast<const float4*>(&u[base + q4]);
        float4 vv = *reinterpret_cast<const float4*>(&vl[base + q4]);
        *reinterpret_cast<float4*>(&su[q4]) = uu;
        sv[q4] = -vv.x; sv[q4+1] = -vv.y; sv[q4+2] = -vv.z; sv[q4+3] = -vv.w;
    }
    __syncthreads();
    const int c = t & 31, q = t >> 5;      // q uniform across half-wave
    const int j = blockIdx.x * 32 + c;
    const float cj = (float)(NN - 1 - 2 * j);
    const float4* su4 = reinterpret_cast<const float4*>(su);
    const float4* sv4 = reinterpret_cast<const float4*>(sv);
    const int i40 = q * (NN / 8) / 4, i41 = i40 + (NN / 8) / 4;
    float m0 = -3.4e38f, m1 = -3.4e38f;
    for (int i4 = i40; i4 < i41; ++i4) {
        float4 uu = su4[i4], vv = sv4[i4];
        m0 = fmaxf(m0, fmaf(uu.x, cj, vv.x));
        m1 = fmaxf(m1, fmaf(uu.y, cj, vv.y));
        m0 = fmaxf(m0, fmaf(uu.z, cj, vv.z));
        m1 = fmaxf(m1, fmaf(uu.w, cj, vv.w));
    }
    pm[q][c] = fmaxf(m0, m1);
    __syncthreads();
    if (t < 32) {
        float m = pm[0][t];
#pragma unroll
        for (int k = 1; k < 8; k++) m = fmaxf(m, pm[k][t]);
        fm[t] = m;
    }
    __syncthreads();
    const float m = fm[c];
    float z0 = 0.f, z1 = 0.f;
    for (int i4 = i40; i4 < i41; ++i4) {
        float4 uu = su4[i4], vv = sv4[i4];
        z0 += EXP2(fmaf(uu.x, cj, vv.x) - m);
        z1 += EXP2(fmaf(uu.y, cj, vv.y) - m);
        z0 += EXP2(fmaf(uu.z, cj, vv.z) - m);
        z1 += EXP2(fmaf(uu.w, cj, vv.w) - m);
    }
    pz[q][c] = z0 + z1;
    __syncthreads();
    if (t < 32) {
        float z = 0.f;
#pragma unroll
        for (int k = 0; k < 8; k++) z += pz[k][t];
        w[base + blockIdx.x * 32 + t] = -fm[t] - log2f(z);
    }
}

// ---------------------------------------------------------------------------
// Kernel C: out[b,i,j] = exp2(fma(u_i, c_j, w_j - v_i)).
// Grid (NN/1024, NN/32, nb), block 256; thread owns 4 consecutive columns
// (float4 store), loops 32 rows. 2 VALU + 1 trans per element; store-bound.
__global__ __launch_bounds__(256) void k_out(const float* __restrict__ u,
                                             const float* __restrict__ vl,
                                             const float* __restrict__ w,
                                             float* __restrict__ out, int nb) {
    __shared__ float su[32], sv[32];
    const int b = blockIdx.z, jc = blockIdx.x, t = threadIdx.x;
    const int i0 = blockIdx.y * 32;
    if (t < 32) {
        su[t] = u[(size_t)b * NN + i0 + t];
        sv[t] = vl[(size_t)b * NN + i0 + t];
    }
    const int j = jc * 1024 + t * 4;
    const float4 w4 = *reinterpret_cast<const float4*>(w + (size_t)b * NN + j);
    const float c0 = (float)(NN - 1 - 2 * j);
    const float c1 = c0 - 2.f, c2 = c0 - 4.f, c3 = c0 - 6.f;
    __syncthreads();
    float* orow = out + ((size_t)b * NN + i0) * NN + j;
#pragma unroll 4
    for (int r = 0; r < 32; r++) {
        const float ui = su[r], vi = sv[r];
        float4 o;
        o.x = EXP2(fmaf(ui, c0, w4.x - vi));
        o.y = EXP2(fmaf(ui, c1, w4.y - vi));
        o.z = EXP2(fmaf(ui, c2, w4.z - vi));
        o.w = EXP2(fmaf(ui, c3, w4.w - vi));
        *reinterpret_cast<float4*>(orow + (size_t)r * NN) = o;
    }
}

// ---------------------------------------------------------------------------
extern "C" void kernel_launch(void* const* d_in, const int* in_sizes, int n_in,
                              void* d_out, int out_size, void* d_ws, size_t ws_size,
                              hipStream_t stream) {
    const float* scores = (const float*)d_in[0];
    float* out = (float*)d_out;
    const int nb = in_sizes[0] / NN;          // 4 batches
    const size_t S = (size_t)nb * NN;

    float* ws = (float*)d_ws;                 // 3*S floats = 192 KiB
    float* u  = ws;
    float* vl = u + S;
    float* w  = vl + S;

    hipLaunchKernelGGL(k_rows, dim3(NN / 64, nb), dim3(256), 0, stream,
                       scores, u, vl, nb);
    hipLaunchKernelGGL(k_cols, dim3(NN / 32, nb), dim3(256), 0, stream,
                       u, vl, w, nb);
    hipLaunchKernelGGL(k_out, dim3(NN / 1024, NN / 32, nb), dim3(256), 0, stream,
                       u, vl, w, out, nb);
}